// Round 15
// baseline (138.504 us; speedup 1.0000x reference)
//
#include <hip/hip_runtime.h>

typedef __attribute__((ext_vector_type(8))) __bf16 bf16x8;
typedef __attribute__((ext_vector_type(4))) float f32x4;
typedef __attribute__((ext_vector_type(4))) int i32x4;
typedef __attribute__((ext_vector_type(2))) int i32x2;
typedef __attribute__((ext_vector_type(4))) unsigned short u16x4;
typedef __attribute__((ext_vector_type(8))) unsigned short u16x8;
typedef unsigned short u16;
typedef unsigned int u32;

#define DEVI __device__ __forceinline__

constexpr int CB = 4;      // batch
constexpr int CC = 512;    // channels
constexpr int CH = 8;      // heads
constexpr int CD = 64;     // head dim
constexpr int CN = 1024;   // tokens (32*32)
constexpr float L2E = 1.44269504088896f;

DEVI u16 f2bf(float f) {
    u32 u = __builtin_bit_cast(u32, f);
    u = (u + 0x7FFFu + ((u >> 16) & 1u)) >> 16;
    return (u16)u;
}
DEVI float bf2f(u16 u) {
    return __builtin_bit_cast(float, (u32)u << 16);
}
DEVI u16 f2bf_c(float f) {           // compiler cvt (fuses into v_cvt_pk_bf16_f32)
    return __builtin_bit_cast(u16, (__bf16)f);
}
DEVI float exp2_fast(float x) {      // v_exp_f32 computes 2^x
    float r;
    asm("v_exp_f32 %0, %1" : "=v"(r) : "v"(x));
    return r;
}

// swizzled byte offsets: XOR row low bits into the 16B-unit index
DEVI int swzA(int row, int col16) {   // 256B-stride rows ([64][128] bf16)
    return (row * 256 + col16 * 16) ^ ((row & 7) << 4);
}
DEVI int swzB(int row, int col16) {   // 128B-stride rows ([*][64] bf16)
    return (row * 128 + col16 * 16) ^ ((row & 7) << 4);
}

DEVI bf16x8 ldfrag(const u16* base, int byteoff) {
    const i32x4* p = reinterpret_cast<const i32x4*>(reinterpret_cast<const char*>(base) + byteoff);
    return __builtin_bit_cast(bf16x8, *p);
}
DEVI void st8(u16* base, int byteoff, i32x2 v) {
    *reinterpret_cast<i32x2*>(reinterpret_cast<char*>(base) + byteoff) = v;
}
DEVI void async16(u16* lds, const u16* g) {
    __builtin_amdgcn_global_load_lds(
        (const __attribute__((address_space(1))) unsigned int*)g,
        (__attribute__((address_space(3))) unsigned int*)lds,
        16, 0, 0);
}

// ---------------------------------------------------------------------------
// convX (+ fused convW): q{1,2,3} f32 [b][c][n] -> XT bf16 [p][b][n][c];
// W f32 -> Wbf bf16 (128 f32x4 per block, threads < 128).
// ---------------------------------------------------------------------------
__global__ __launch_bounds__(256) void mqf_convx_kernel(
    const float* __restrict__ q1, const float* __restrict__ q2, const float* __restrict__ q3,
    const float* __restrict__ Wq, const float* __restrict__ Wk, const float* __restrict__ Wv,
    u16* __restrict__ XT, u16* __restrict__ Wbf)
{
    __shared__ u16 T[64 * 66];   // [c_local][n_local] stride 66
    const int t = threadIdx.x;
    const int n0 = blockIdx.x * 64, c0 = blockIdx.y * 64;
    const int p = blockIdx.z >> 2, b = blockIdx.z & 3;
    const float* X = (p == 0 ? q1 : p == 1 ? q2 : q3) + (size_t)b * CC * CN;
    u16* dst = XT + (size_t)(p * CB + b) * CN * CC;

    // fused W conversion: 1536 blocks x 128 f32x4 = full 3*512*512
    if (t < 128) {
        int bid = blockIdx.x + (blockIdx.y << 4) + (blockIdx.z << 7);
        int idx = (bid * 128 + t) * 4;
        int pw = idx >> 18;
        int off = idx & 0x3FFFF;
        const float* W = (pw == 0 ? Wq : pw == 1 ? Wk : Wv);
        f32x4 v = *reinterpret_cast<const f32x4*>(W + off);
        u16x4 pk;
        #pragma unroll
        for (int j = 0; j < 4; ++j) pk[j] = f2bf(v[j]);
        *reinterpret_cast<u16x4*>(Wbf + idx) = pk;
    }

    #pragma unroll
    for (int pass = 0; pass < 4; ++pass) {
        int idx = pass * 256 + t;
        int cl = idx >> 4, nl = (idx & 15) * 4;
        f32x4 v = *reinterpret_cast<const f32x4*>(X + (size_t)(c0 + cl) * CN + n0 + nl);
        u32 lo = (u32)f2bf(v[0]) | ((u32)f2bf(v[1]) << 16);
        u32 hi = (u32)f2bf(v[2]) | ((u32)f2bf(v[3]) << 16);
        *reinterpret_cast<u32*>(&T[cl * 66 + nl]) = lo;
        *reinterpret_cast<u32*>(&T[cl * 66 + nl + 2]) = hi;
    }
    __syncthreads();
    #pragma unroll
    for (int pass = 0; pass < 2; ++pass) {
        int idx = pass * 256 + t;
        int nl = idx >> 3, g = idx & 7;
        u16x8 pk;
        #pragma unroll
        for (int j = 0; j < 8; ++j) pk[j] = T[(g * 8 + j) * 66 + nl];
        *reinterpret_cast<u16x8*>(dst + (size_t)(n0 + nl) * CC + c0 + g * 8) = pk;
    }
}

// ---------------------------------------------------------------------------
// Projection GEMM v2: 64(o) x 128(n) tile, BK=64, 768 blocks = 3/CU exact.
// Double-buffered global_load_lds staging (1 barrier/step), LDS f32 epilogue
// with packed dual-layout stores.
// ---------------------------------------------------------------------------
__global__ __launch_bounds__(256) void mqf_gemm_kernel(
    const u16* __restrict__ Wbf, const u16* __restrict__ XT,
    const float* __restrict__ bq, const float* __restrict__ bk, const float* __restrict__ bv,
    u16* __restrict__ projN, u16* __restrict__ projT)
{
    __shared__ __align__(16) char lds_raw[49152];
    u16* At0 = (u16*)lds_raw;          // 8 KB  [64][64]
    u16* At1 = At0 + 4096;             // 8 KB
    u16* Bt0 = At0 + 8192;             // 16 KB [128][64]
    u16* Bt1 = Bt0 + 8192;             // 16 KB
    float* Tb = (float*)lds_raw;       // 33 KB epilogue [64][129]

    const int t = threadIdx.x;
    const int w = t >> 6, l = t & 63;
    const int li = l & 15, hi = l >> 4;

    // bijective XCD swizzle: 768 blocks, 96/XCD
    int id = blockIdx.x + (blockIdx.y << 3) + (blockIdx.z << 6);
    int nid = (id & 7) * 96 + (id >> 3);
    const int n0 = (nid & 7) * 128;
    const int o0 = ((nid >> 3) & 7) * 64;
    const int pb = nid >> 6;
    const int p = pb >> 2, b = pb & 3;

    const u16* A = Wbf + (size_t)p * CC * CC;                 // [o][c]
    const u16* B = XT + (size_t)(p * CB + b) * CN * CC;       // [n][c]
    const float* bm = (p == 0 ? bq : p == 1 ? bk : bv);
    u16* oN = projN + (size_t)(p * CB + b) * CC * CN;
    u16* oT = projT + (size_t)(p * CB + b) * CN * CC;

    const int sj = t & 7;   // 16B unit within 128B row

    auto issueDMA = [&](int step, u16* AtW, u16* BtW) {
        int c0 = step * 64;
        #pragma unroll
        for (int q = 0; q < 2; ++q) {
            int idx = q * 256 + t;
            int row = idx >> 3;
            int col = (sj ^ (row & 7)) * 8;
            async16(AtW + idx * 8, A + (size_t)(o0 + row) * CC + c0 + col);
        }
        #pragma unroll
        for (int q = 0; q < 4; ++q) {
            int idx = q * 256 + t;
            int row = idx >> 3;
            int col = (sj ^ (row & 7)) * 8;
            async16(BtW + idx * 8, B + (size_t)(n0 + row) * CC + c0 + col);
        }
    };

    const f32x4 fz = {0.f, 0.f, 0.f, 0.f};
    f32x4 acc[4][2];
    #pragma unroll
    for (int m = 0; m < 4; ++m)
        #pragma unroll
        for (int s = 0; s < 2; ++s) acc[m][s] = fz;

    issueDMA(0, At0, Bt0);
    __syncthreads();

    for (int step = 0; step < 8; ++step) {
        u16* AtC = (step & 1) ? At1 : At0;
        u16* BtC = (step & 1) ? Bt1 : Bt0;
        if (step < 7) issueDMA(step + 1, (step & 1) ? At0 : At1, (step & 1) ? Bt0 : Bt1);

        __builtin_amdgcn_s_setprio(1);
        #pragma unroll
        for (int kk = 0; kk < 2; ++kk) {
            bf16x8 af[4], bfr[2];
            #pragma unroll
            for (int m = 0; m < 4; ++m)
                af[m] = ldfrag(AtC, swzB(m * 16 + li, kk * 4 + hi));
            #pragma unroll
            for (int s = 0; s < 2; ++s)
                bfr[s] = ldfrag(BtC, swzB(w * 32 + s * 16 + li, kk * 4 + hi));
            #pragma unroll
            for (int m = 0; m < 4; ++m)
                #pragma unroll
                for (int s = 0; s < 2; ++s)
                    acc[m][s] = __builtin_amdgcn_mfma_f32_16x16x32_bf16(af[m], bfr[s], acc[m][s], 0, 0, 0);
        }
        __builtin_amdgcn_s_setprio(0);
        __syncthreads();
    }

    // epilogue: acc (+bias) -> Tb f32 [64][129], then packed dual-layout
    #pragma unroll
    for (int m = 0; m < 4; ++m) {
        #pragma unroll
        for (int r = 0; r < 4; ++r) {
            int orow = m * 16 + hi * 4 + r;
            float bias = bm[o0 + orow];
            #pragma unroll
            for (int s = 0; s < 2; ++s)
                Tb[orow * 129 + w * 32 + s * 16 + li] = acc[m][s][r] + bias;
        }
    }
    __syncthreads();
    {
        int row = t >> 2, nbase = (t & 3) * 32;       // oN: [o][n]
        #pragma unroll
        for (int j = 0; j < 4; ++j) {
            u16x8 pk;
            #pragma unroll
            for (int i = 0; i < 8; ++i) pk[i] = f2bf_c(Tb[row * 129 + nbase + j * 8 + i]);
            *reinterpret_cast<u16x8*>(oN + (size_t)(o0 + row) * CN + n0 + nbase + j * 8) = pk;
        }
        int nrow = t >> 1, obase = (t & 1) * 32;      // oT: [n][o]
        #pragma unroll
        for (int j = 0; j < 4; ++j) {
            u16x8 pk;
            #pragma unroll
            for (int i = 0; i < 8; ++i) pk[i] = f2bf_c(Tb[(obase + j * 8 + i) * 129 + nrow]);
            *reinterpret_cast<u16x8*>(oT + (size_t)(n0 + nrow) * CC + o0 + obase + j * 8) = pk;
        }
    }
}

// ---------------------------------------------------------------------------
// Attention v15: 128 threads (2 waves), QBLK=128, each wave owns 64 n-cols
// (4 qsets) -> every Kt/Vt fragment read feeds 4 MFMAs; per-CU LDS read
// traffic halves vs R13 at the SAME barrier count (16 tiles, KVBLK=64).
// Grid 768 = exactly 3 blocks/CU. Swapped QK; P in regs (Vt m-permuted);
// max-free exp2 softmax, sm-split; K via global_load_lds pre-swizzled src;
// V reg-staged. K/V dbuf; one barrier per tile.
// ---------------------------------------------------------------------------
__global__ __launch_bounds__(128, 2) void mqf_attn_kernel(
    const u16* __restrict__ projN, const u16* __restrict__ projT,
    const float* __restrict__ rel_h, const float* __restrict__ rel_w,
    float* __restrict__ out)
{
    __shared__ __align__(16) u16 Kt[2][64 * 128];  // [m][dd] swizzled (2x16KB)
    __shared__ __align__(16) u16 Vt[2][64 * 64];   // [d][m-perm] swizzled (2x8KB)

    const int t = threadIdx.x;            // 0..127
    const int w = t >> 6, l = t & 63;     // 2 waves
    const int li = l & 15, hi = l >> 4;

    // bijective XCD swizzle: 768 blocks, 96/XCD
    int id = blockIdx.x + (blockIdx.y << 3) + (blockIdx.z << 8);
    int nid = (id & 7) * 96 + (id >> 3);
    const int n0 = (nid & 7) * 128;
    const int by = (nid >> 3) & 31;
    const int br = nid >> 8;
    const int b = by >> 3, h = by & 7;

    const int ai = br, bi = (br + 1) % 3, vi = (br + 2) % 3;
    const size_t tsz = (size_t)CB * CC * CN;
    const u16* aT = projT + ai * tsz + (size_t)b * CN * CC;  // [n][o]
    const u16* bT = projT + bi * tsz + (size_t)b * CN * CC;  // [n][o]
    const u16* vN = projN + vi * tsz + (size_t)b * CC * CN;  // [o][n]

    // ---- Q' fragments (4 qsets) in registers, scaled by log2(e).
    bf16x8 qf[4][4];
    #pragma unroll
    for (int g = 0; g < 4; ++g) {
        const int nq = n0 + w * 64 + g * 16 + li;
        #pragma unroll
        for (int kk = 0; kk < 2; ++kk) {
            u16x8 raw = *reinterpret_cast<const u16x8*>(
                aT + (size_t)nq * CC + h * CD + kk * 32 + hi * 8);
            u16x8 pk;
            #pragma unroll
            for (int j = 0; j < 8; ++j) pk[j] = f2bf_c(bf2f(raw[j]) * L2E);
            qf[g][kk] = __builtin_bit_cast(bf16x8, pk);
        }
        #pragma unroll
        for (int kk = 2; kk < 4; ++kk) {
            u16x8 pk;
            #pragma unroll
            for (int j = 0; j < 8; ++j) {
                int d = (kk - 2) * 32 + hi * 8 + j;
                float f = rel_h[(h * CD + d) * 32 + (nq & 31)]
                        + rel_w[(h * CD + d) * 32 + (nq >> 5)];
                pk[j] = f2bf_c(f * L2E);
            }
            qf[g][kk] = __builtin_bit_cast(bf16x8, pk);
        }
    }

    const f32x4 fz = {0.f, 0.f, 0.f, 0.f};
    f32x4 oacc[4][4];   // [g][dg]
    #pragma unroll
    for (int g = 0; g < 4; ++g)
        #pragma unroll
        for (int dg = 0; dg < 4; ++dg) oacc[g][dg] = fz;
    float lsum[4] = {0.f, 0.f, 0.f, 0.f};

    // ---- V staging: thread t covers rows vrow, vrow+32; 16 m each (vc)
    i32x4 vreg[4];
    const int vrow = t >> 2, vc = (t & 3) * 16;
    const int vb0 = ((vc >> 5) << 6) + (((vc >> 4) & 1) << 3);

    auto loadV = [&](int m1) {
        const u16* rv = vN + (size_t)(h * CD + vrow) * CN + m1 + vc;
        vreg[0] = *reinterpret_cast<const i32x4*>(rv);
        vreg[1] = *reinterpret_cast<const i32x4*>(rv + 8);
        vreg[2] = *reinterpret_cast<const i32x4*>(rv + (size_t)32 * CN);
        vreg[3] = *reinterpret_cast<const i32x4*>(rv + (size_t)32 * CN + 8);
    };
    auto writeV = [&](u16* VtW) {
        #pragma unroll
        for (int half = 0; half < 2; ++half) {
            int r = vrow + half * 32;
            int sw = (r & 7) << 4;
            i32x2 a0 = {vreg[half * 2][0], vreg[half * 2][1]};
            i32x2 a1 = {vreg[half * 2][2], vreg[half * 2][3]};
            i32x2 b0 = {vreg[half * 2 + 1][0], vreg[half * 2 + 1][1]};
            i32x2 b1 = {vreg[half * 2 + 1][2], vreg[half * 2 + 1][3]};
            st8(VtW, (r * 128 + vb0) ^ sw, a0);
            st8(VtW, (r * 128 + vb0 + 16) ^ sw, a1);
            st8(VtW, (r * 128 + vb0 + 32) ^ sw, b0);
            st8(VtW, (r * 128 + vb0 + 48) ^ sw, b1);
        }
    };
    // K direct-to-LDS DMA: linear dest, inverse-swizzled per-lane source.
    auto issueKdma = [&](int m1, u16* KtW) {
        #pragma unroll
        for (int i = 0; i < 8; ++i) {
            int u = i * 128 + t;
            int row = u >> 4, cu = u & 15;
            int col16 = cu ^ (row & 7);
            const u16* src = ((col16 & 8) ? aT : bT)
                + (size_t)(m1 + row) * CC + h * CD + (col16 & 7) * 8;
            async16(KtW + u * 8, src);
        }
    };

    loadV(0);
    writeV(Vt[0]);
    issueKdma(0, Kt[0]);
    loadV(64);
    __syncthreads();

    for (int tt = 0; tt < 16; ++tt) {
        if (tt < 15) {
            writeV(Vt[(tt + 1) & 1]);
            issueKdma((tt + 1) * 64, Kt[(tt + 1) & 1]);
        }
        if (tt < 14) loadV((tt + 2) * 64);

        const u16* KtC = Kt[tt & 1];
        const u16* VtC = Vt[tt & 1];

        // ---- QK^T: e[g][s][r] = energy[m = s*16+hi*4+r][n = qset g col]
        f32x4 e[4][4];
        #pragma unroll
        for (int g = 0; g < 4; ++g)
            #pragma unroll
            for (int s = 0; s < 4; ++s) e[g][s] = fz;
        __builtin_amdgcn_s_setprio(1);
        #pragma unroll
        for (int kk = 0; kk < 4; ++kk) {
            #pragma unroll
            for (int s = 0; s < 2; ++s) {
                bf16x8 af = ldfrag(KtC, swzA(s * 16 + li, kk * 4 + hi));
                #pragma unroll
                for (int g = 0; g < 4; ++g)
                    e[g][s] = __builtin_amdgcn_mfma_f32_16x16x32_bf16(af, qf[g][kk], e[g][s], 0, 0, 0);
            }
        }
        #pragma unroll
        for (int kk = 0; kk < 4; ++kk) {
            #pragma unroll
            for (int s = 2; s < 4; ++s) {
                bf16x8 af = ldfrag(KtC, swzA(s * 16 + li, kk * 4 + hi));
                #pragma unroll
                for (int g = 0; g < 4; ++g)
                    e[g][s] = __builtin_amdgcn_mfma_f32_16x16x32_bf16(af, qf[g][kk], e[g][s], 0, 0, 0);
            }
        }
        __builtin_amdgcn_s_setprio(0);

        // ---- softmax half A (s=0,1) -> pa0
        bf16x8 pa0[4], pa1[4];
        #pragma unroll
        for (int g = 0; g < 4; ++g) {
            float ts = 0.f;
            u16x8 pk;
            #pragma unroll
            for (int r = 0; r < 4; ++r) {
                float p0 = exp2_fast(e[g][0][r]);
                float p1 = exp2_fast(e[g][1][r]);
                ts += p0 + p1;
                pk[r] = f2bf_c(p0);
                pk[4 + r] = f2bf_c(p1);
            }
            lsum[g] += ts;
            pa0[g] = __builtin_bit_cast(bf16x8, pk);
        }
        // ---- PV kk=0 (m 0..31)
        __builtin_amdgcn_s_setprio(1);
        #pragma unroll
        for (int dg = 0; dg < 4; ++dg) {
            bf16x8 vf = ldfrag(VtC, swzB(dg * 16 + li, hi));
            #pragma unroll
            for (int g = 0; g < 4; ++g)
                oacc[g][dg] = __builtin_amdgcn_mfma_f32_16x16x32_bf16(vf, pa0[g], oacc[g][dg], 0, 0, 0);
        }
        __builtin_amdgcn_s_setprio(0);
        // ---- softmax half B (s=2,3) -> pa1
        #pragma unroll
        for (int g = 0; g < 4; ++g) {
            float ts = 0.f;
            u16x8 pk;
            #pragma unroll
            for (int r = 0; r < 4; ++r) {
                float p0 = exp2_fast(e[g][2][r]);
                float p1 = exp2_fast(e[g][3][r]);
                ts += p0 + p1;
                pk[r] = f2bf_c(p0);
                pk[4 + r] = f2bf_c(p1);
            }
            lsum[g] += ts;
            pa1[g] = __builtin_bit_cast(bf16x8, pk);
        }
        // ---- PV kk=1 (m 32..63)
        __builtin_amdgcn_s_setprio(1);
        #pragma unroll
        for (int dg = 0; dg < 4; ++dg) {
            bf16x8 vf = ldfrag(VtC, swzB(dg * 16 + li, 4 + hi));
            #pragma unroll
            for (int g = 0; g < 4; ++g)
                oacc[g][dg] = __builtin_amdgcn_mfma_f32_16x16x32_bf16(vf, pa1[g], oacc[g][dg], 0, 0, 0);
        }
        __builtin_amdgcn_s_setprio(0);
        __syncthreads();
    }

    // ---- epilogue: reduce lsum across hi groups once, normalize, store
    #pragma unroll
    for (int g = 0; g < 4; ++g) {
        float lt = lsum[g];
        lt += __shfl_xor(lt, 16, 64);
        lt += __shfl_xor(lt, 32, 64);
        float inv = 1.f / lt;
        float* outp = out + ((size_t)(br * CB + b) * CC + h * CD) * CN
                    + n0 + w * 64 + g * 16 + li;
        #pragma unroll
        for (int dg = 0; dg < 4; ++dg) {
            #pragma unroll
            for (int r = 0; r < 4; ++r) {
                int drow = dg * 16 + hi * 4 + r;
                outp[(size_t)drow * CN] = oacc[g][dg][r] * inv;
            }
        }
    }
}

extern "C" void kernel_launch(void* const* d_in, const int* in_sizes, int n_in,
                              void* d_out, int out_size, void* d_ws, size_t ws_size,
                              hipStream_t stream) {
    const float* q1 = (const float*)d_in[0];
    const float* q2 = (const float*)d_in[1];
    const float* q3 = (const float*)d_in[2];
    const float* Wq = (const float*)d_in[3];
    const float* bq = (const float*)d_in[4];
    const float* Wk = (const float*)d_in[5];
    const float* bk = (const float*)d_in[6];
    const float* Wv = (const float*)d_in[7];
    const float* bv = (const float*)d_in[8];
    const float* rh = (const float*)d_in[9];
    const float* rw = (const float*)d_in[10];

    u16* XT    = (u16*)d_ws;                          // 12.6 MB
    u16* Wbf   = XT + (size_t)3 * CB * CN * CC;       // 1.5 MB
    u16* projN = Wbf + (size_t)3 * CC * CC;           // 12.6 MB
    u16* projT = projN + (size_t)3 * CB * CC * CN;    // 12.6 MB
    float* outp = (float*)d_out;

    dim3 gc(CN / 64, CC / 64, 12);
    mqf_convx_kernel<<<gc, 256, 0, stream>>>(q1, q2, q3, Wq, Wk, Wv, XT, Wbf);
    dim3 gg(CN / 128, CC / 64, 12);
    mqf_gemm_kernel<<<gg, 256, 0, stream>>>(Wbf, XT, bq, bk, bv, projN, projT);
    dim3 ga(CN / 128, CB * CH, 3);
    mqf_attn_kernel<<<ga, 128, 0, stream>>>(projN, projT, rh, rw, outp);
}

// Round 16
// 72.204 us; speedup vs baseline: 1.9182x; 1.9182x over previous
//
#include <hip/hip_runtime.h>

typedef __attribute__((ext_vector_type(8))) __bf16 bf16x8;
typedef __attribute__((ext_vector_type(4))) float f32x4;
typedef __attribute__((ext_vector_type(4))) int i32x4;
typedef __attribute__((ext_vector_type(2))) int i32x2;
typedef __attribute__((ext_vector_type(4))) unsigned short u16x4;
typedef __attribute__((ext_vector_type(8))) unsigned short u16x8;
typedef unsigned short u16;
typedef unsigned int u32;

#define DEVI __device__ __forceinline__

constexpr int CB = 4;      // batch
constexpr int CC = 512;    // channels
constexpr int CH = 8;      // heads
constexpr int CD = 64;     // head dim
constexpr int CN = 1024;   // tokens (32*32)
constexpr float L2E = 1.44269504088896f;

DEVI u16 f2bf(float f) {
    u32 u = __builtin_bit_cast(u32, f);
    u = (u + 0x7FFFu + ((u >> 16) & 1u)) >> 16;
    return (u16)u;
}
DEVI float bf2f(u16 u) {
    return __builtin_bit_cast(float, (u32)u << 16);
}
DEVI u16 f2bf_c(float f) {           // compiler cvt (fuses into v_cvt_pk_bf16_f32)
    return __builtin_bit_cast(u16, (__bf16)f);
}
DEVI float exp2_fast(float x) {      // v_exp_f32 via schedulable intrinsic
    return __builtin_amdgcn_exp2f(x);
}

// swizzled byte offsets: XOR bits 4-6 with row low bits (16B-unit swizzle)
DEVI int swzA(int row, int col16) {   // 256B-stride rows ([64][128] bf16)
    return (row * 256 + col16 * 16) ^ ((row & 7) << 4);
}
DEVI int swzB(int row, int col16) {   // 128B-stride rows ([*][64] bf16)
    return (row * 128 + col16 * 16) ^ ((row & 7) << 4);
}

DEVI bf16x8 ldfrag(const u16* base, int byteoff) {
    const i32x4* p = reinterpret_cast<const i32x4*>(reinterpret_cast<const char*>(base) + byteoff);
    return __builtin_bit_cast(bf16x8, *p);
}
DEVI void st8(u16* base, int byteoff, i32x2 v) {
    *reinterpret_cast<i32x2*>(reinterpret_cast<char*>(base) + byteoff) = v;
}
DEVI void async16(u16* lds, const u16* g) {
    __builtin_amdgcn_global_load_lds(
        (const __attribute__((address_space(1))) unsigned int*)g,
        (__attribute__((address_space(3))) unsigned int*)lds,
        16, 0, 0);
}

// ---------------------------------------------------------------------------
// convX (+ fused convW): q{1,2,3} f32 [b][c][n] -> XT bf16 [p][b][n][c];
// W f32 -> Wbf bf16 (128 f32x4 per block, threads < 128).
// ---------------------------------------------------------------------------
__global__ __launch_bounds__(256) void mqf_convx_kernel(
    const float* __restrict__ q1, const float* __restrict__ q2, const float* __restrict__ q3,
    const float* __restrict__ Wq, const float* __restrict__ Wk, const float* __restrict__ Wv,
    u16* __restrict__ XT, u16* __restrict__ Wbf)
{
    __shared__ u16 T[64 * 66];   // [c_local][n_local] stride 66
    const int t = threadIdx.x;
    const int n0 = blockIdx.x * 64, c0 = blockIdx.y * 64;
    const int p = blockIdx.z >> 2, b = blockIdx.z & 3;
    const float* X = (p == 0 ? q1 : p == 1 ? q2 : q3) + (size_t)b * CC * CN;
    u16* dst = XT + (size_t)(p * CB + b) * CN * CC;

    // fused W conversion: 1536 blocks x 128 f32x4 = full 3*512*512
    if (t < 128) {
        int bid = blockIdx.x + (blockIdx.y << 4) + (blockIdx.z << 7);
        int idx = (bid * 128 + t) * 4;
        int pw = idx >> 18;
        int off = idx & 0x3FFFF;
        const float* W = (pw == 0 ? Wq : pw == 1 ? Wk : Wv);
        f32x4 v = *reinterpret_cast<const f32x4*>(W + off);
        u16x4 pk;
        #pragma unroll
        for (int j = 0; j < 4; ++j) pk[j] = f2bf(v[j]);
        *reinterpret_cast<u16x4*>(Wbf + idx) = pk;
    }

    #pragma unroll
    for (int pass = 0; pass < 4; ++pass) {
        int idx = pass * 256 + t;
        int cl = idx >> 4, nl = (idx & 15) * 4;
        f32x4 v = *reinterpret_cast<const f32x4*>(X + (size_t)(c0 + cl) * CN + n0 + nl);
        u32 lo = (u32)f2bf(v[0]) | ((u32)f2bf(v[1]) << 16);
        u32 hi = (u32)f2bf(v[2]) | ((u32)f2bf(v[3]) << 16);
        *reinterpret_cast<u32*>(&T[cl * 66 + nl]) = lo;
        *reinterpret_cast<u32*>(&T[cl * 66 + nl + 2]) = hi;
    }
    __syncthreads();
    #pragma unroll
    for (int pass = 0; pass < 2; ++pass) {
        int idx = pass * 256 + t;
        int nl = idx >> 3, g = idx & 7;
        u16x8 pk;
        #pragma unroll
        for (int j = 0; j < 8; ++j) pk[j] = T[(g * 8 + j) * 66 + nl];
        *reinterpret_cast<u16x8*>(dst + (size_t)(n0 + nl) * CC + c0 + g * 8) = pk;
    }
}

// ---------------------------------------------------------------------------
// Projection GEMM v2: 64(o) x 128(n) tile, BK=64, 768 blocks = 3/CU exact.
// Double-buffered global_load_lds staging (1 barrier/step), LDS f32 epilogue
// with packed dual-layout stores.
// ---------------------------------------------------------------------------
__global__ __launch_bounds__(256) void mqf_gemm_kernel(
    const u16* __restrict__ Wbf, const u16* __restrict__ XT,
    const float* __restrict__ bq, const float* __restrict__ bk, const float* __restrict__ bv,
    u16* __restrict__ projN, u16* __restrict__ projT)
{
    __shared__ __align__(16) char lds_raw[49152];
    u16* At0 = (u16*)lds_raw;          // 8 KB  [64][64]
    u16* At1 = At0 + 4096;             // 8 KB
    u16* Bt0 = At0 + 8192;             // 16 KB [128][64]
    u16* Bt1 = Bt0 + 8192;             // 16 KB
    float* Tb = (float*)lds_raw;       // 33 KB epilogue [64][129]

    const int t = threadIdx.x;
    const int w = t >> 6, l = t & 63;
    const int li = l & 15, hi = l >> 4;

    // bijective XCD swizzle: 768 blocks, 96/XCD
    int id = blockIdx.x + (blockIdx.y << 3) + (blockIdx.z << 6);
    int nid = (id & 7) * 96 + (id >> 3);
    const int n0 = (nid & 7) * 128;
    const int o0 = ((nid >> 3) & 7) * 64;
    const int pb = nid >> 6;
    const int p = pb >> 2, b = pb & 3;

    const u16* A = Wbf + (size_t)p * CC * CC;                 // [o][c]
    const u16* B = XT + (size_t)(p * CB + b) * CN * CC;       // [n][c]
    const float* bm = (p == 0 ? bq : p == 1 ? bk : bv);
    u16* oN = projN + (size_t)(p * CB + b) * CC * CN;
    u16* oT = projT + (size_t)(p * CB + b) * CN * CC;

    const int sj = t & 7;   // 16B unit within 128B row

    auto issueDMA = [&](int step, u16* AtW, u16* BtW) {
        int c0 = step * 64;
        #pragma unroll
        for (int q = 0; q < 2; ++q) {
            int idx = q * 256 + t;
            int row = idx >> 3;
            int col = (sj ^ (row & 7)) * 8;
            async16(AtW + idx * 8, A + (size_t)(o0 + row) * CC + c0 + col);
        }
        #pragma unroll
        for (int q = 0; q < 4; ++q) {
            int idx = q * 256 + t;
            int row = idx >> 3;
            int col = (sj ^ (row & 7)) * 8;
            async16(BtW + idx * 8, B + (size_t)(n0 + row) * CC + c0 + col);
        }
    };

    const f32x4 fz = {0.f, 0.f, 0.f, 0.f};
    f32x4 acc[4][2];
    #pragma unroll
    for (int m = 0; m < 4; ++m)
        #pragma unroll
        for (int s = 0; s < 2; ++s) acc[m][s] = fz;

    issueDMA(0, At0, Bt0);
    __syncthreads();

    for (int step = 0; step < 8; ++step) {
        u16* AtC = (step & 1) ? At1 : At0;
        u16* BtC = (step & 1) ? Bt1 : Bt0;
        if (step < 7) issueDMA(step + 1, (step & 1) ? At0 : At1, (step & 1) ? Bt0 : Bt1);

        __builtin_amdgcn_s_setprio(1);
        #pragma unroll
        for (int kk = 0; kk < 2; ++kk) {
            bf16x8 af[4], bfr[2];
            #pragma unroll
            for (int m = 0; m < 4; ++m)
                af[m] = ldfrag(AtC, swzB(m * 16 + li, kk * 4 + hi));
            #pragma unroll
            for (int s = 0; s < 2; ++s)
                bfr[s] = ldfrag(BtC, swzB(w * 32 + s * 16 + li, kk * 4 + hi));
            #pragma unroll
            for (int m = 0; m < 4; ++m)
                #pragma unroll
                for (int s = 0; s < 2; ++s)
                    acc[m][s] = __builtin_amdgcn_mfma_f32_16x16x32_bf16(af[m], bfr[s], acc[m][s], 0, 0, 0);
        }
        __builtin_amdgcn_s_setprio(0);
        __syncthreads();
    }

    // epilogue: acc (+bias) -> Tb f32 [64][129], then packed dual-layout
    #pragma unroll
    for (int m = 0; m < 4; ++m) {
        #pragma unroll
        for (int r = 0; r < 4; ++r) {
            int orow = m * 16 + hi * 4 + r;
            float bias = bm[o0 + orow];
            #pragma unroll
            for (int s = 0; s < 2; ++s)
                Tb[orow * 129 + w * 32 + s * 16 + li] = acc[m][s][r] + bias;
        }
    }
    __syncthreads();
    {
        int row = t >> 2, nbase = (t & 3) * 32;       // oN: [o][n]
        #pragma unroll
        for (int j = 0; j < 4; ++j) {
            u16x8 pk;
            #pragma unroll
            for (int i = 0; i < 8; ++i) pk[i] = f2bf_c(Tb[row * 129 + nbase + j * 8 + i]);
            *reinterpret_cast<u16x8*>(oN + (size_t)(o0 + row) * CN + n0 + nbase + j * 8) = pk;
        }
        int nrow = t >> 1, obase = (t & 1) * 32;      // oT: [n][o]
        #pragma unroll
        for (int j = 0; j < 4; ++j) {
            u16x8 pk;
            #pragma unroll
            for (int i = 0; i < 8; ++i) pk[i] = f2bf_c(Tb[(obase + j * 8 + i) * 129 + nrow]);
            *reinterpret_cast<u16x8*>(oT + (size_t)(n0 + nrow) * CC + o0 + obase + j * 8) = pk;
        }
    }
}

// ---------------------------------------------------------------------------
// Attention (R13 anchor): block = 128 Q rows (4 waves x 2 qsets), one
// (br,b,h). Swapped QK; P in registers (Vt m-permuted); max-free exp2
// softmax split per kk-half with PV kk=0 between the halves, setprio toggles
// separating VALU and MFMA sections (required: toggle-less mixing miscompiled
// in R12). K via global_load_lds (pre-swizzled source); V reg-staged.
// K/V LDS double-buffered; one barrier per tile.
// ---------------------------------------------------------------------------
__global__ __launch_bounds__(256, 3) void mqf_attn_kernel(
    const u16* __restrict__ projN, const u16* __restrict__ projT,
    const float* __restrict__ rel_h, const float* __restrict__ rel_w,
    float* __restrict__ out)
{
    __shared__ __align__(16) u16 Kt[2][64 * 128];  // [m][dd] swizzled (2x16KB)
    __shared__ __align__(16) u16 Vt[2][64 * 64];   // [d][m-perm] swizzled (2x8KB)

    const int t = threadIdx.x;
    const int w = t >> 6, l = t & 63;
    const int li = l & 15, hi = l >> 4;

    int id = blockIdx.x + (blockIdx.y << 3) + (blockIdx.z << 8);
    int nid = (id & 7) * 96 + (id >> 3);
    const int n0 = (nid & 7) * 128;
    const int by = (nid >> 3) & 31;
    const int br = nid >> 8;
    const int b = by >> 3, h = by & 7;

    const int ai = br, bi = (br + 1) % 3, vi = (br + 2) % 3;
    const size_t tsz = (size_t)CB * CC * CN;
    const u16* aT = projT + ai * tsz + (size_t)b * CN * CC;  // [n][o]
    const u16* bT = projT + bi * tsz + (size_t)b * CN * CC;  // [n][o]
    const u16* vN = projN + vi * tsz + (size_t)b * CC * CN;  // [o][n]

    // ---- Q' fragments (2 qsets) in registers, scaled by log2(e).
    bf16x8 qf[2][4];
    #pragma unroll
    for (int g = 0; g < 2; ++g) {
        const int nq = n0 + (w * 2 + g) * 16 + li;
        #pragma unroll
        for (int kk = 0; kk < 2; ++kk) {
            u16x8 raw = *reinterpret_cast<const u16x8*>(
                aT + (size_t)nq * CC + h * CD + kk * 32 + hi * 8);
            u16x8 pk;
            #pragma unroll
            for (int j = 0; j < 8; ++j) pk[j] = f2bf_c(bf2f(raw[j]) * L2E);
            qf[g][kk] = __builtin_bit_cast(bf16x8, pk);
        }
        #pragma unroll
        for (int kk = 2; kk < 4; ++kk) {
            u16x8 pk;
            #pragma unroll
            for (int j = 0; j < 8; ++j) {
                int d = (kk - 2) * 32 + hi * 8 + j;
                float f = rel_h[(h * CD + d) * 32 + (nq & 31)]
                        + rel_w[(h * CD + d) * 32 + (nq >> 5)];
                pk[j] = f2bf_c(f * L2E);
            }
            qf[g][kk] = __builtin_bit_cast(bf16x8, pk);
        }
    }

    const f32x4 fz = {0.f, 0.f, 0.f, 0.f};
    f32x4 oacc[2][4];
    #pragma unroll
    for (int g = 0; g < 2; ++g)
        #pragma unroll
        for (int dg = 0; dg < 4; ++dg) oacc[g][dg] = fz;
    float lsum[2] = {0.f, 0.f};

    // ---- V staging regs (8B m-permute -> must go through VGPRs)
    i32x4 vreg[2];
    const int vrow = t >> 3, vc = (t & 7) * 8;
    const int vb0 = ((vc >> 5) << 6) + (((vc >> 2) & 3) << 4) + (((vc >> 4) & 1) << 3);

    auto loadV = [&](int m1) {
        const u16* rv = vN + (size_t)(h * CD + vrow) * CN + m1;
        vreg[0] = *reinterpret_cast<const i32x4*>(rv + vc);
        vreg[1] = *reinterpret_cast<const i32x4*>(rv + (size_t)32 * CN + vc);
    };
    auto writeV = [&](u16* VtW) {
        i32x2 lo0 = {vreg[0][0], vreg[0][1]}, hi0 = {vreg[0][2], vreg[0][3]};
        int r0 = vrow, r1 = vrow + 32;
        st8(VtW, (r0 * 128 + vb0) ^ ((r0 & 7) << 4), lo0);
        st8(VtW, (r0 * 128 + vb0 + 16) ^ ((r0 & 7) << 4), hi0);
        i32x2 lo1 = {vreg[1][0], vreg[1][1]}, hi1 = {vreg[1][2], vreg[1][3]};
        st8(VtW, (r1 * 128 + vb0) ^ ((r1 & 7) << 4), lo1);
        st8(VtW, (r1 * 128 + vb0 + 16) ^ ((r1 & 7) << 4), hi1);
    };
    auto issueKdma = [&](int m1, u16* KtW) {
        #pragma unroll
        for (int i = 0; i < 4; ++i) {
            int row = w * 16 + i * 4 + hi;
            int col16 = li ^ (row & 7);
            const u16* src = ((li & 8) ? aT : bT)
                + (size_t)(m1 + row) * CC + h * CD + (col16 & 7) * 8;
            async16(KtW + w * 2048 + i * 512 + l * 8, src);
        }
    };

    loadV(0);
    writeV(Vt[0]);
    issueKdma(0, Kt[0]);
    loadV(64);
    __syncthreads();

    for (int tt = 0; tt < 16; ++tt) {
        if (tt < 15) {
            writeV(Vt[(tt + 1) & 1]);
            issueKdma((tt + 1) * 64, Kt[(tt + 1) & 1]);
        }
        if (tt < 14) loadV((tt + 2) * 64);

        const u16* KtC = Kt[tt & 1];
        const u16* VtC = Vt[tt & 1];

        // ---- QK^T in two s-halves
        f32x4 e[2][4];
        #pragma unroll
        for (int s = 0; s < 4; ++s) { e[0][s] = fz; e[1][s] = fz; }
        __builtin_amdgcn_s_setprio(1);
        #pragma unroll
        for (int kk = 0; kk < 4; ++kk) {
            #pragma unroll
            for (int s = 0; s < 2; ++s) {
                bf16x8 af = ldfrag(KtC, swzA(s * 16 + li, kk * 4 + hi));
                e[0][s] = __builtin_amdgcn_mfma_f32_16x16x32_bf16(af, qf[0][kk], e[0][s], 0, 0, 0);
                e[1][s] = __builtin_amdgcn_mfma_f32_16x16x32_bf16(af, qf[1][kk], e[1][s], 0, 0, 0);
            }
        }
        #pragma unroll
        for (int kk = 0; kk < 4; ++kk) {
            #pragma unroll
            for (int s = 2; s < 4; ++s) {
                bf16x8 af = ldfrag(KtC, swzA(s * 16 + li, kk * 4 + hi));
                e[0][s] = __builtin_amdgcn_mfma_f32_16x16x32_bf16(af, qf[0][kk], e[0][s], 0, 0, 0);
                e[1][s] = __builtin_amdgcn_mfma_f32_16x16x32_bf16(af, qf[1][kk], e[1][s], 0, 0, 0);
            }
        }
        __builtin_amdgcn_s_setprio(0);

        // ---- softmax half A (s=0,1) -> pa0
        bf16x8 pa0[2], pa1[2];
        #pragma unroll
        for (int g = 0; g < 2; ++g) {
            float ts = 0.f;
            u16x8 pk;
            #pragma unroll
            for (int r = 0; r < 4; ++r) {
                float p0 = exp2_fast(e[g][0][r]);
                float p1 = exp2_fast(e[g][1][r]);
                ts += p0 + p1;
                pk[r] = f2bf_c(p0);
                pk[4 + r] = f2bf_c(p1);
            }
            lsum[g] += ts;
            pa0[g] = __builtin_bit_cast(bf16x8, pk);
        }
        // ---- PV kk=0 (m 0..31)
        __builtin_amdgcn_s_setprio(1);
        #pragma unroll
        for (int dg = 0; dg < 4; ++dg) {
            bf16x8 vf = ldfrag(VtC, swzB(dg * 16 + li, hi));
            oacc[0][dg] = __builtin_amdgcn_mfma_f32_16x16x32_bf16(vf, pa0[0], oacc[0][dg], 0, 0, 0);
            oacc[1][dg] = __builtin_amdgcn_mfma_f32_16x16x32_bf16(vf, pa0[1], oacc[1][dg], 0, 0, 0);
        }
        __builtin_amdgcn_s_setprio(0);
        // ---- softmax half B (s=2,3) -> pa1
        #pragma unroll
        for (int g = 0; g < 2; ++g) {
            float ts = 0.f;
            u16x8 pk;
            #pragma unroll
            for (int r = 0; r < 4; ++r) {
                float p0 = exp2_fast(e[g][2][r]);
                float p1 = exp2_fast(e[g][3][r]);
                ts += p0 + p1;
                pk[r] = f2bf_c(p0);
                pk[4 + r] = f2bf_c(p1);
            }
            lsum[g] += ts;
            pa1[g] = __builtin_bit_cast(bf16x8, pk);
        }
        // ---- PV kk=1 (m 32..63)
        __builtin_amdgcn_s_setprio(1);
        #pragma unroll
        for (int dg = 0; dg < 4; ++dg) {
            bf16x8 vf = ldfrag(VtC, swzB(dg * 16 + li, 4 + hi));
            oacc[0][dg] = __builtin_amdgcn_mfma_f32_16x16x32_bf16(vf, pa1[0], oacc[0][dg], 0, 0, 0);
            oacc[1][dg] = __builtin_amdgcn_mfma_f32_16x16x32_bf16(vf, pa1[1], oacc[1][dg], 0, 0, 0);
        }
        __builtin_amdgcn_s_setprio(0);
        __syncthreads();
    }

    // ---- epilogue: reduce lsum across hi groups once, normalize, store
    #pragma unroll
    for (int g = 0; g < 2; ++g) {
        float lt = lsum[g];
        lt += __shfl_xor(lt, 16, 64);
        lt += __shfl_xor(lt, 32, 64);
        float inv = 1.f / lt;
        float* outp = out + ((size_t)(br * CB + b) * CC + h * CD) * CN
                    + n0 + (w * 2 + g) * 16 + li;
        #pragma unroll
        for (int dg = 0; dg < 4; ++dg) {
            #pragma unroll
            for (int r = 0; r < 4; ++r) {
                int drow = dg * 16 + hi * 4 + r;
                outp[(size_t)drow * CN] = oacc[g][dg][r] * inv;
            }
        }
    }
}

extern "C" void kernel_launch(void* const* d_in, const int* in_sizes, int n_in,
                              void* d_out, int out_size, void* d_ws, size_t ws_size,
                              hipStream_t stream) {
    const float* q1 = (const float*)d_in[0];
    const float* q2 = (const float*)d_in[1];
    const float* q3 = (const float*)d_in[2];
    const float* Wq = (const float*)d_in[3];
    const float* bq = (const float*)d_in[4];
    const float* Wk = (const float*)d_in[5];
    const float* bk = (const float*)d_in[6];
    const float* Wv = (const float*)d_in[7];
    const float* bv = (const float*)d_in[8];
    const float* rh = (const float*)d_in[9];
    const float* rw = (const float*)d_in[10];

    u16* XT    = (u16*)d_ws;                          // 12.6 MB
    u16* Wbf   = XT + (size_t)3 * CB * CN * CC;       // 1.5 MB
    u16* projN = Wbf + (size_t)3 * CC * CC;           // 12.6 MB
    u16* projT = projN + (size_t)3 * CB * CC * CN;    // 12.6 MB
    float* outp = (float*)d_out;

    dim3 gc(CN / 64, CC / 64, 12);
    mqf_convx_kernel<<<gc, 256, 0, stream>>>(q1, q2, q3, Wq, Wk, Wv, XT, Wbf);
    dim3 gg(CN / 128, CC / 64, 12);
    mqf_gemm_kernel<<<gg, 256, 0, stream>>>(Wbf, XT, bq, bk, bv, projN, projT);
    dim3 ga(CN / 128, CB * CH, 3);
    mqf_attn_kernel<<<ga, 256, 0, stream>>>(projN, projT, rh, rw, outp);
}